// Round 1
// baseline (174.224 us; speedup 1.0000x reference)
//
#include <hip/hip_runtime.h>
#include <hip/hip_bf16.h>

#define MDIM 8192
#define KDIM 1024
#define NDIM 1024
#define NEXP 8
#define BM 128
#define BN 128
#define BK 32
#define LDSS 40  // LDS row stride in bf16 elems: 80 B — 16B-aligned for b128, <=2-way banks (free)

typedef __attribute__((ext_vector_type(8))) short bf16x8;
typedef __attribute__((ext_vector_type(4))) float floatx4;

static __device__ __forceinline__ unsigned short f2b(float f) {
    // fp32 -> bf16 round-to-nearest-even (inputs are finite; no NaN path needed)
    unsigned int u = __float_as_uint(f);
    return (unsigned short)((u + 0x7fffu + ((u >> 16) & 1u)) >> 16);
}

static __device__ __forceinline__ void cvt_store4(unsigned short* dst, float4 v) {
    ushort4 u;
    u.x = f2b(v.x); u.y = f2b(v.y); u.z = f2b(v.z); u.w = f2b(v.w);
    *reinterpret_cast<ushort4*>(dst) = u;  // 8 B ds_write
}

__global__ __launch_bounds__(256, 2)
void grouped_gemm_bf16(const float* __restrict__ a,
                       const float* __restrict__ b,
                       const int* __restrict__ seg_indptr,
                       const int* __restrict__ widx,
                       float* __restrict__ c)
{
    __shared__ unsigned short As[BM * LDSS];
    __shared__ unsigned short Bs[BN * LDSS];

    // ---- block -> (segment s, m-tile within segment, n-tile); tiles never straddle segments
    const int NTN = NDIM / BN;  // 8
    int rem = (int)blockIdx.x;
    int s = -1, m0 = 0, seg_end = 0, n0 = 0;
    for (int i = 0; i < NEXP; ++i) {
        int ps = seg_indptr[i], pe = seg_indptr[i + 1];
        int nt = ((pe - ps + BM - 1) / BM) * NTN;
        if (rem < nt) {
            s = i; m0 = ps + (rem / NTN) * BM; n0 = (rem % NTN) * BN; seg_end = pe;
            break;
        }
        rem -= nt;
    }
    if (s < 0) return;  // surplus block (worst-case grid)

    const float* __restrict__ be = b + (size_t)widx[s] * (size_t)(NDIM * KDIM);

    const int tid = (int)threadIdx.x;
    // staging: thread t -> rows r0+32u (u=0..3), float4 at k-offset kc; coalesced 128B/row-seg
    const int r0 = tid >> 3;       // 0..31
    const int kc = (tid & 7) * 4;  // 0..28

    int arow[4];
#pragma unroll
    for (int u = 0; u < 4; ++u) {
        int r = m0 + r0 + 32 * u;           // may run past seg_end in a partial tile:
        arow[u] = r < MDIM ? r : MDIM - 1;  // clamp for safety; stores are masked below
    }

    const int lane = tid & 63;
    const int wave = tid >> 6;       // 4 waves in 2x2 -> each computes 64x64
    const int wm = (wave & 1) * 64;
    const int wn = (wave >> 1) * 64;
    const int fr = lane & 15;
    const int quad = lane >> 4;

    floatx4 acc[4][4] = {};

    // prologue loads for k0 = 0
    float4 av[4], bv[4];
#pragma unroll
    for (int u = 0; u < 4; ++u) {
        av[u] = *reinterpret_cast<const float4*>(a + (size_t)arow[u] * KDIM + kc);
        bv[u] = *reinterpret_cast<const float4*>(be + (size_t)(n0 + r0 + 32 * u) * KDIM + kc);
    }

    for (int k0 = 0; k0 < KDIM; k0 += BK) {
        __syncthreads();  // previous iteration's ds_reads complete before overwrite
#pragma unroll
        for (int u = 0; u < 4; ++u) {
            cvt_store4(&As[(r0 + 32 * u) * LDSS + kc], av[u]);
            cvt_store4(&Bs[(r0 + 32 * u) * LDSS + kc], bv[u]);
        }
        // prefetch next k-slab into registers (branchless dummy k=0 reload on last iter)
        const int kn = (k0 + BK < KDIM) ? (k0 + BK) : 0;
#pragma unroll
        for (int u = 0; u < 4; ++u) {
            av[u] = *reinterpret_cast<const float4*>(a + (size_t)arow[u] * KDIM + kn + kc);
            bv[u] = *reinterpret_cast<const float4*>(be + (size_t)(n0 + r0 + 32 * u) * KDIM + kn + kc);
        }
        __syncthreads();

        bf16x8 af[4], bf[4];
#pragma unroll
        for (int mi = 0; mi < 4; ++mi)
            af[mi] = *reinterpret_cast<const bf16x8*>(&As[(wm + mi * 16 + fr) * LDSS + quad * 8]);
#pragma unroll
        for (int ni = 0; ni < 4; ++ni)
            bf[ni] = *reinterpret_cast<const bf16x8*>(&Bs[(wn + ni * 16 + fr) * LDSS + quad * 8]);
#pragma unroll
        for (int mi = 0; mi < 4; ++mi)
#pragma unroll
            for (int ni = 0; ni < 4; ++ni)
                acc[mi][ni] = __builtin_amdgcn_mfma_f32_16x16x32_bf16(af[mi], bf[ni], acc[mi][ni], 0, 0, 0);
    }

    // ---- epilogue: C/D layout col=lane&15, row=quad*4+reg (m89-verified); mask partial rows
#pragma unroll
    for (int mi = 0; mi < 4; ++mi) {
        const int rbase = m0 + wm + mi * 16 + quad * 4;
#pragma unroll
        for (int ni = 0; ni < 4; ++ni) {
            const int col = n0 + wn + ni * 16 + fr;
#pragma unroll
            for (int j = 0; j < 4; ++j) {
                const int row = rbase + j;
                if (row < seg_end)
                    c[(size_t)row * NDIM + col] = acc[mi][ni][j];
            }
        }
    }
}

extern "C" void kernel_launch(void* const* d_in, const int* in_sizes, int n_in,
                              void* d_out, int out_size, void* d_ws, size_t ws_size,
                              hipStream_t stream) {
    const float* a          = (const float*)d_in[0];
    const float* b          = (const float*)d_in[1];
    // d_in[2] = c (zeros, fully overwritten: segments cover [0, M)) — unused
    // d_in[3] = batch_size (=8), d_in[4] = weight_column_major (=1) — fixed-shape, unused
    const int*   seg_indptr = (const int*)d_in[5];
    const int*   widx       = (const int*)d_in[6];
    float*       out        = (float*)d_out;

    // worst-case tile count: sum ceil(len_s/128) <= 64+7 = 71 row-tiles, x8 col-tiles = 568
    dim3 grid(568), block(256);
    hipLaunchKernelGGL(grouped_gemm_bf16, grid, block, 0, stream,
                       a, b, seg_indptr, widx, out);
}

// Round 2
// 168.044 us; speedup vs baseline: 1.0368x; 1.0368x over previous
//
#include <hip/hip_runtime.h>
#include <hip/hip_bf16.h>
#include <stdint.h>

#define MDIM 8192
#define KDIM 1024
#define NDIM 1024
#define NEXP 8
#define BM 128
#define BN 128
#define BK 32
#define LDSS 40  // fallback-kernel LDS stride

typedef __attribute__((ext_vector_type(8))) short bf16x8;
typedef __attribute__((ext_vector_type(4))) float floatx4;
typedef __attribute__((ext_vector_type(8))) unsigned short ushort8;

static __device__ __forceinline__ unsigned short f2b(float f) {
    // fp32 -> bf16 round-to-nearest-even (inputs finite)
    unsigned int u = __float_as_uint(f);
    return (unsigned short)((u + 0x7fffu + ((u >> 16) & 1u)) >> 16);
}

// ---------------- pass 1: fp32 -> bf16 (a and b) into workspace ----------------
// total 16,777,216 elems, 8/thread -> 2,097,152 threads = 8192 blocks x 256 (exact)
__global__ __launch_bounds__(256)
void cvt_bf16(const float* __restrict__ a, const float* __restrict__ b,
              unsigned short* __restrict__ wa, unsigned short* __restrict__ wb)
{
    const long t  = (long)blockIdx.x * 256 + threadIdx.x;
    const long NA = (long)MDIM * KDIM / 8;  // vec8 count in a
    const float* src; unsigned short* dst; long v;
    if (t < NA) { src = a; dst = wa; v = t; }
    else        { src = b; dst = wb; v = t - NA; }
    const float4 lo = ((const float4*)src)[2 * v];
    const float4 hi = ((const float4*)src)[2 * v + 1];
    ushort8 o;
    o[0] = f2b(lo.x); o[1] = f2b(lo.y); o[2] = f2b(lo.z); o[3] = f2b(lo.w);
    o[4] = f2b(hi.x); o[5] = f2b(hi.y); o[6] = f2b(hi.z); o[7] = f2b(hi.w);
    ((ushort8*)dst)[v] = o;  // 16 B store
}

// ---------------- pass 2: m97-structure bf16 GEMM with global_load_lds ----------
#define GLDS(gp, lp) __builtin_amdgcn_global_load_lds(                        \
    (const __attribute__((address_space(1))) unsigned int*)(gp),              \
    (__attribute__((address_space(3))) unsigned int*)(lp), 16, 0, 0)

__global__ __launch_bounds__(256, 2)
void grouped_gemm_ws(const unsigned short* __restrict__ A,   // [M,K] bf16
                     const unsigned short* __restrict__ B,   // [E,N,K] bf16
                     const int* __restrict__ seg_indptr,
                     const int* __restrict__ widx,
                     float* __restrict__ c)
{
    // unpadded row-major [row][k], 64 B row stride — required by global_load_lds
    __shared__ unsigned short As[BM * BK];
    __shared__ unsigned short Bs[BN * BK];

    const int NTN = NDIM / BN;  // 8
    int rem = (int)blockIdx.x;
    int s = -1, m0 = 0, seg_end = 0, n0 = 0;
    for (int i = 0; i < NEXP; ++i) {
        int ps = seg_indptr[i], pe = seg_indptr[i + 1];
        int nt = ((pe - ps + BM - 1) / BM) * NTN;
        if (rem < nt) { s = i; m0 = ps + (rem / NTN) * BM; n0 = (rem % NTN) * BN; seg_end = pe; break; }
        rem -= nt;
    }
    if (s < 0) return;

    const unsigned short* __restrict__ be = B + (size_t)widx[s] * (size_t)(NDIM * KDIM);

    const int tid  = (int)threadIdx.x;
    const int wave = tid >> 6;
    const int lane = tid & 63;
    // staging geometry: inst j covers rows [j*64, j*64+64); thread -> row j*64 + tid/4,
    // 16B chunk (tid&3)*8 bf16. LDS dest = wave-uniform base + lane*16 (HW) == row*64 + chunk*16. ✓
    const int srow = tid >> 2;        // 0..63
    const int skc  = (tid & 3) * 8;   // bf16 offset in k
    int arow0 = m0 + srow;       if (arow0 >= MDIM) arow0 = MDIM - 1;  // clamp; masked at store
    int arow1 = m0 + 64 + srow;  if (arow1 >= MDIM) arow1 = MDIM - 1;
    const int brow0 = n0 + srow, brow1 = n0 + 64 + srow;
    const int ldsoff = wave * 16 * BK;  // wave-uniform part of LDS dest (elements)

    const int wm = (wave & 1) * 64;
    const int wn = (wave >> 1) * 64;
    const int fr = lane & 15;
    const int quad = lane >> 4;

    floatx4 acc[4][4] = {};

    const unsigned short* aptr0 = A  + (size_t)arow0 * KDIM + skc;
    const unsigned short* aptr1 = A  + (size_t)arow1 * KDIM + skc;
    const unsigned short* bptr0 = be + (size_t)brow0 * KDIM + skc;
    const unsigned short* bptr1 = be + (size_t)brow1 * KDIM + skc;

    for (int k0 = 0; k0 < KDIM; k0 += BK) {
        GLDS(aptr0 + k0, &As[ldsoff]);
        GLDS(aptr1 + k0, &As[64 * BK + ldsoff]);
        GLDS(bptr0 + k0, &Bs[ldsoff]);
        GLDS(bptr1 + k0, &Bs[64 * BK + ldsoff]);
        __syncthreads();  // drains vmcnt -> LDS tiles complete

        bf16x8 af[4], bf[4];
#pragma unroll
        for (int mi = 0; mi < 4; ++mi)
            af[mi] = *reinterpret_cast<const bf16x8*>(&As[(wm + mi * 16 + fr) * BK + quad * 8]);
#pragma unroll
        for (int ni = 0; ni < 4; ++ni)
            bf[ni] = *reinterpret_cast<const bf16x8*>(&Bs[(wn + ni * 16 + fr) * BK + quad * 8]);
#pragma unroll
        for (int mi = 0; mi < 4; ++mi)
#pragma unroll
            for (int ni = 0; ni < 4; ++ni)
                acc[mi][ni] = __builtin_amdgcn_mfma_f32_16x16x32_bf16(af[mi], bf[ni], acc[mi][ni], 0, 0, 0);
        __syncthreads();  // ds_reads done before next iter's global_load_lds overwrites
    }

    // epilogue: C/D layout col=lane&15, row=quad*4+reg (m89-verified); mask partial rows
#pragma unroll
    for (int mi = 0; mi < 4; ++mi) {
        const int rbase = m0 + wm + mi * 16 + quad * 4;
#pragma unroll
        for (int ni = 0; ni < 4; ++ni) {
            const int col = n0 + wn + ni * 16 + fr;
#pragma unroll
            for (int j = 0; j < 4; ++j) {
                const int row = rbase + j;
                if (row < seg_end)
                    c[(size_t)row * NDIM + col] = acc[mi][ni][j];
            }
        }
    }
}

// ---------------- fallback (R1 fused kernel) if workspace is too small ----------
__global__ __launch_bounds__(256, 2)
void grouped_gemm_fused(const float* __restrict__ a, const float* __restrict__ b,
                        const int* __restrict__ seg_indptr, const int* __restrict__ widx,
                        float* __restrict__ c)
{
    __shared__ unsigned short As[BM * LDSS];
    __shared__ unsigned short Bs[BN * LDSS];
    const int NTN = NDIM / BN;
    int rem = (int)blockIdx.x;
    int s = -1, m0 = 0, seg_end = 0, n0 = 0;
    for (int i = 0; i < NEXP; ++i) {
        int ps = seg_indptr[i], pe = seg_indptr[i + 1];
        int nt = ((pe - ps + BM - 1) / BM) * NTN;
        if (rem < nt) { s = i; m0 = ps + (rem / NTN) * BM; n0 = (rem % NTN) * BN; seg_end = pe; break; }
        rem -= nt;
    }
    if (s < 0) return;
    const float* __restrict__ be = b + (size_t)widx[s] * (size_t)(NDIM * KDIM);
    const int tid = (int)threadIdx.x;
    const int r0 = tid >> 3;
    const int kc = (tid & 7) * 4;
    int arow[4];
#pragma unroll
    for (int u = 0; u < 4; ++u) {
        int r = m0 + r0 + 32 * u;
        arow[u] = r < MDIM ? r : MDIM - 1;
    }
    const int lane = tid & 63;
    const int wave = tid >> 6;
    const int wm = (wave & 1) * 64;
    const int wn = (wave >> 1) * 64;
    const int fr = lane & 15;
    const int quad = lane >> 4;
    floatx4 acc[4][4] = {};
    float4 av[4], bv[4];
#pragma unroll
    for (int u = 0; u < 4; ++u) {
        av[u] = *reinterpret_cast<const float4*>(a + (size_t)arow[u] * KDIM + kc);
        bv[u] = *reinterpret_cast<const float4*>(be + (size_t)(n0 + r0 + 32 * u) * KDIM + kc);
    }
    for (int k0 = 0; k0 < KDIM; k0 += BK) {
        __syncthreads();
#pragma unroll
        for (int u = 0; u < 4; ++u) {
            ushort4 ua, ub;
            ua.x = f2b(av[u].x); ua.y = f2b(av[u].y); ua.z = f2b(av[u].z); ua.w = f2b(av[u].w);
            ub.x = f2b(bv[u].x); ub.y = f2b(bv[u].y); ub.z = f2b(bv[u].z); ub.w = f2b(bv[u].w);
            *reinterpret_cast<ushort4*>(&As[(r0 + 32 * u) * LDSS + kc]) = ua;
            *reinterpret_cast<ushort4*>(&Bs[(r0 + 32 * u) * LDSS + kc]) = ub;
        }
        const int kn = (k0 + BK < KDIM) ? (k0 + BK) : 0;
#pragma unroll
        for (int u = 0; u < 4; ++u) {
            av[u] = *reinterpret_cast<const float4*>(a + (size_t)arow[u] * KDIM + kn + kc);
            bv[u] = *reinterpret_cast<const float4*>(be + (size_t)(n0 + r0 + 32 * u) * KDIM + kn + kc);
        }
        __syncthreads();
        bf16x8 af[4], bf[4];
#pragma unroll
        for (int mi = 0; mi < 4; ++mi)
            af[mi] = *reinterpret_cast<const bf16x8*>(&As[(wm + mi * 16 + fr) * LDSS + quad * 8]);
#pragma unroll
        for (int ni = 0; ni < 4; ++ni)
            bf[ni] = *reinterpret_cast<const bf16x8*>(&Bs[(wn + ni * 16 + fr) * LDSS + quad * 8]);
#pragma unroll
        for (int mi = 0; mi < 4; ++mi)
#pragma unroll
            for (int ni = 0; ni < 4; ++ni)
                acc[mi][ni] = __builtin_amdgcn_mfma_f32_16x16x32_bf16(af[mi], bf[ni], acc[mi][ni], 0, 0, 0);
    }
#pragma unroll
    for (int mi = 0; mi < 4; ++mi) {
        const int rbase = m0 + wm + mi * 16 + quad * 4;
#pragma unroll
        for (int ni = 0; ni < 4; ++ni) {
            const int col = n0 + wn + ni * 16 + fr;
#pragma unroll
            for (int j = 0; j < 4; ++j) {
                const int row = rbase + j;
                if (row < seg_end)
                    c[(size_t)row * NDIM + col] = acc[mi][ni][j];
            }
        }
    }
}

extern "C" void kernel_launch(void* const* d_in, const int* in_sizes, int n_in,
                              void* d_out, int out_size, void* d_ws, size_t ws_size,
                              hipStream_t stream) {
    const float* a          = (const float*)d_in[0];
    const float* b          = (const float*)d_in[1];
    const int*   seg_indptr = (const int*)d_in[5];
    const int*   widx       = (const int*)d_in[6];
    float*       out        = (float*)d_out;

    const size_t need = (size_t)(MDIM + NEXP * NDIM) * KDIM * sizeof(unsigned short); // 32 MiB
    if (ws_size >= need) {
        unsigned short* wa = (unsigned short*)d_ws;                       // [M,K] bf16
        unsigned short* wb = wa + (size_t)MDIM * KDIM;                    // [E,N,K] bf16
        hipLaunchKernelGGL(cvt_bf16, dim3(8192), dim3(256), 0, stream, a, b, wa, wb);
        hipLaunchKernelGGL(grouped_gemm_ws, dim3(568), dim3(256), 0, stream,
                           wa, wb, seg_indptr, widx, out);
    } else {
        hipLaunchKernelGGL(grouped_gemm_fused, dim3(568), dim3(256), 0, stream,
                           a, b, seg_indptr, widx, out);
    }
}